// Round 4
// baseline (480.302 us; speedup 1.0000x reference)
//
#include <hip/hip_runtime.h>
#include <hip/hip_cooperative_groups.h>
#include <math.h>

namespace cg = cooperative_groups;

#define N_NODES 100000
#define N_EDGES 500000
#define E_HID   64
#define R_HID   32
#define N_RELS  500
#define EPSF    1e-16f
#define D_OUT   224   // 64 (x) + 160 (e_features)

#define NBLK 512      // 2 blocks/CU -> co-resident for cooperative launch
#define NTHR 512      // 8 waves/block

// Single cooperative kernel: scores -> hist -> atomic-offset scan -> place -> aggregate.
__global__ __launch_bounds__(NTHR, 4)
void fused_all_kernel(const float* __restrict__ x,
                      const int* __restrict__ ei,
                      const int* __restrict__ ej,
                      const int* __restrict__ rel,
                      const float* __restrict__ rel_emb,
                      const float* __restrict__ ww,
                      float* __restrict__ out,
                      float* __restrict__ s_i,
                      float* __restrict__ s_j,
                      float* __restrict__ s_r,
                      int* __restrict__ count,
                      int* __restrict__ starts,
                      int* __restrict__ gcursor,
                      int4* __restrict__ pack) {
    cg::grid_group grid = cg::this_grid();
    __shared__ int lds[NTHR];
    __shared__ int base_s;
    const int tid     = threadIdx.x;
    const int gtid    = blockIdx.x * blockDim.x + tid;
    const int gstride = gridDim.x * blockDim.x;        // multiple of 64

    // ---- P0: zero count/cursor; node score scalars; rel score scalars ----
    for (int t = gtid; t < N_NODES; t += gstride) count[t] = 0;
    if (gtid == 0) *gcursor = 0;
    // s_i[n]=x[n]·w[0:64], s_j[n]=x[n]·w[96:160]; 64-lane groups (bounds are
    // multiples of 64 and gstride%64==0 -> wave-uniform loop, shfl safe)
    for (int t = gtid; t < N_NODES * E_HID; t += gstride) {
        int node = t >> 6, lane = t & 63;
        float v = x[t];                         // t == node*64+lane
        float a = v * ww[lane];
        float b = v * ww[96 + lane];
        #pragma unroll
        for (int off = 32; off > 0; off >>= 1) {
            a += __shfl_down(a, off);
            b += __shfl_down(b, off);
        }
        if (lane == 0) { s_i[node] = a; s_j[node] = b; }
    }
    // s_r[r]=rel_emb[r]·w[64:96]; 32-lane groups
    for (int t = gtid; t < N_RELS * R_HID; t += gstride) {
        int r = t >> 5, lane = t & 31;
        float a = rel_emb[t] * ww[64 + lane];   // t == r*32+lane
        #pragma unroll
        for (int off = 16; off > 0; off >>= 1) a += __shfl_down(a, off, 32);
        if (lane == 0) s_r[r] = a;
    }
    grid.sync();

    // ---- P1: histogram of destinations ----
    for (int e = gtid; e < N_EDGES; e += gstride) atomicAdd(&count[ei[e]], 1);
    grid.sync();

    // ---- P2: segment starts via block-prefix + one global atomic per block.
    // Segment ORDER is arbitrary (doesn't affect the result) -> no global scan.
    {
        const int nchunk = (N_NODES + NTHR - 1) / NTHR;   // 196 <= gridDim
        for (int c = blockIdx.x; c < nchunk; c += gridDim.x) {
            int gid = c * NTHR + tid;
            int v = (gid < N_NODES) ? count[gid] : 0;
            lds[tid] = v;
            __syncthreads();
            #pragma unroll
            for (int off = 1; off < NTHR; off <<= 1) {
                int t2 = (tid >= off) ? lds[tid - off] : 0;
                __syncthreads();
                lds[tid] += t2;
                __syncthreads();
            }
            if (tid == NTHR - 1) base_s = atomicAdd(gcursor, lds[NTHR - 1]);
            __syncthreads();
            if (gid < N_NODES) starts[gid] = base_s + lds[tid] - v;  // exclusive
            __syncthreads();
        }
    }
    grid.sync();

    // ---- P3: place edge payload {src, rel, exp(att)} into CSR slots.
    // Post-increments starts[] (afterwards starts[d] == segment end).
    for (int e = gtid; e < N_EDGES; e += gstride) {
        int d   = ei[e];
        int src = ej[e];
        int r   = rel[e];
        float se = __expf(s_i[d] + s_r[r] + s_j[src]);  // |att| small: no max pass
        int pos = atomicAdd(&starts[d], 1);
        pack[pos] = make_int4(src, r, __float_as_int(se), 0);
    }
    grid.sync();

    // ---- P4: per-node aggregate, one 64-lane wave per node, x4 unrolled ----
    {
        const int wid    = gtid >> 6;
        const int lane   = gtid & 63;
        const int rlane  = lane & 31;          // lanes>=32: dummy accr, never stored
        const int nwaves = gstride >> 6;
        for (int node = wid; node < N_NODES; node += nwaves) {
            int cnt = count[node];
            int end = starts[node];
            int beg = end - cnt;
            float S = 0.0f, accx = 0.0f, accr = 0.0f;
            int k = 0;
            for (; k + 4 <= cnt; k += 4) {
                int4 p0 = pack[beg + k + 0];
                int4 p1 = pack[beg + k + 1];
                int4 p2 = pack[beg + k + 2];
                int4 p3 = pack[beg + k + 3];
                float x0 = x[(size_t)p0.x * E_HID + lane];
                float x1 = x[(size_t)p1.x * E_HID + lane];
                float x2 = x[(size_t)p2.x * E_HID + lane];
                float x3 = x[(size_t)p3.x * E_HID + lane];
                float r0 = rel_emb[p0.y * R_HID + rlane];
                float r1 = rel_emb[p1.y * R_HID + rlane];
                float r2 = rel_emb[p2.y * R_HID + rlane];
                float r3 = rel_emb[p3.y * R_HID + rlane];
                float se0 = __int_as_float(p0.z), se1 = __int_as_float(p1.z);
                float se2 = __int_as_float(p2.z), se3 = __int_as_float(p3.z);
                S    += (se0 + se1) + (se2 + se3);
                accx += se0 * x0 + se1 * x1 + se2 * x2 + se3 * x3;
                accr += se0 * r0 + se1 * r1 + se2 * r2 + se3 * r3;
            }
            for (; k < cnt; k++) {
                int4 p = pack[beg + k];
                float se = __int_as_float(p.z);
                S    += se;
                accx += se * x[(size_t)p.x * E_HID + lane];
                accr += se * rel_emb[p.y * R_HID + rlane];
            }
            float wv = 1.0f / (S + EPSF);
            float xv = x[(size_t)node * E_HID + lane];
            float* o = out + (size_t)node * D_OUT;
            o[lane]      = xv;                           // cols 0:64   = x
            o[64 + lane] = fmaxf(S * wv * xv, 0.0f);     // cols 64:128 = relu(a*x)
            if (lane < R_HID)
                o[128 + lane] = fmaxf(accr * wv, 0.0f);  // cols 128:160 = rel part
            o[160 + lane] = fmaxf(accx * wv, 0.0f);      // cols 160:224 = x[ej] part
        }
    }
}

extern "C" void kernel_launch(void* const* d_in, const int* in_sizes, int n_in,
                              void* d_out, int out_size, void* d_ws, size_t ws_size,
                              hipStream_t stream) {
    const float* x        = (const float*)d_in[0];               // [N, 64]
    const int*   edge_all = (const int*)  d_in[1];               // [2, E] flat
    const int*   rel      = (const int*)  d_in[2];               // [E]
    const float* rel_emb  = (const float*)d_in[3];               // [500, 32]
    const float* ww       = (const float*)d_in[4];               // [160]
    float*       out      = (float*)d_out;                       // [N, 224]

    const int* ei = edge_all;            // destinations (group index)
    const int* ej = edge_all + N_EDGES;  // sources

    // workspace layout (pack first -> 16B alignment):
    // pack[E] (int4) | s_i[N] | s_j[N] | s_r[512] | count[N] | starts[N] | gcursor
    int4*  pack    = (int4*)d_ws;                      // 8 MB
    float* s_i     = (float*)(pack + N_EDGES);
    float* s_j     = s_i + N_NODES;
    float* s_r     = s_j + N_NODES;
    int*   count   = (int*)(s_r + 512);
    int*   starts  = count + N_NODES;
    int*   gcursor = starts + N_NODES;

    void* args[] = {
        (void*)&x, (void*)&ei, (void*)&ej, (void*)&rel, (void*)&rel_emb,
        (void*)&ww, (void*)&out, (void*)&s_i, (void*)&s_j, (void*)&s_r,
        (void*)&count, (void*)&starts, (void*)&gcursor, (void*)&pack,
    };
    hipLaunchCooperativeKernel((void*)fused_all_kernel, dim3(NBLK), dim3(NTHR),
                               args, 0, stream);
}

// Round 5
// 193.827 us; speedup vs baseline: 2.4780x; 2.4780x over previous
//
#include <hip/hip_runtime.h>
#include <math.h>

#define N_NODES 100000
#define N_EDGES 500000
#define E_HID   64
#define R_HID   32
#define N_RELS  500
#define EPSF    1e-16f
#define D_OUT   224   // 64 (x) + 160 (e_features)

#define SRC_BITS 17
#define SRC_MASK ((1 << SRC_BITS) - 1)   // src < 100000 < 2^17; rel < 500 < 2^15

// fused pre-kernel block ranges (256 threads/block)
#define NSB  ((N_NODES * 16) / 256)          // 6250: 16 lanes/node, float4 cols
#define RSB  ((N_RELS * 8 + 255) / 256)      // 16:   8 lanes/rel,  float4 cols
#define HB   ((N_EDGES + 255) / 256)         // 1954: histogram
#define PRE_GRID (NSB + RSB + HB)

#define SCAN_B  512
#define SCAN_NB ((N_NODES + SCAN_B - 1) / SCAN_B)   // 196

__device__ __forceinline__ float dot4(float4 a, float4 b) {
    return a.x * b.x + a.y * b.y + a.z * b.z + a.w * b.w;
}
__device__ __forceinline__ float4 axpy4(float s, float4 a, float4 acc) {
    acc.x += s * a.x; acc.y += s * a.y; acc.z += s * a.z; acc.w += s * a.w;
    return acc;
}

// --- Kernel 1 (fused): node scores + rel scores + dest histogram ---
__global__ void fused_pre_kernel(const float* __restrict__ x,
                                 const float* __restrict__ rel_emb,
                                 const float* __restrict__ ww,
                                 const int* __restrict__ ei,
                                 float* __restrict__ s_i,
                                 float* __restrict__ s_j,
                                 float* __restrict__ s_r,
                                 int* __restrict__ count) {
    int b = blockIdx.x;
    if (b < NSB) {
        // s_i[n]=x[n]·w[0:64], s_j[n]=x[n]·w[96:160]; 16 lanes/node, float4
        int t    = b * 256 + threadIdx.x;
        int node = t >> 4, sub = t & 15;
        float4 v  = *(const float4*)&x[node * E_HID + sub * 4];
        float4 wa = *(const float4*)&ww[sub * 4];
        float4 wb = *(const float4*)&ww[96 + sub * 4];
        float a = dot4(v, wa);
        float c = dot4(v, wb);
        #pragma unroll
        for (int off = 8; off > 0; off >>= 1) {
            a += __shfl_down(a, off, 16);
            c += __shfl_down(c, off, 16);
        }
        if (sub == 0) { s_i[node] = a; s_j[node] = c; }
    } else if (b < NSB + RSB) {
        // s_r[r]=rel_emb[r]·w[64:96]; 8 lanes/rel, float4
        int t   = (b - NSB) * 256 + threadIdx.x;
        int r   = t >> 3, sub = t & 7;
        if (r >= N_RELS) return;
        float4 v  = *(const float4*)&rel_emb[r * R_HID + sub * 4];
        float4 wr = *(const float4*)&ww[64 + sub * 4];
        float a = dot4(v, wr);
        #pragma unroll
        for (int off = 4; off > 0; off >>= 1) a += __shfl_down(a, off, 8);
        if (sub == 0) s_r[r] = a;
    } else {
        int e = (b - NSB - RSB) * 256 + threadIdx.x;
        if (e < N_EDGES) atomicAdd(&count[ei[e]], 1);
    }
}

// --- Kernel 2: one-dispatch scan — block prefix + global-cursor atomic.
// Segment ORDER is arbitrary (only relabels pack slots) -> no hierarchy needed.
__global__ void scan_kernel(const int* __restrict__ count,
                            int* __restrict__ starts,
                            int* __restrict__ gcursor) {
    __shared__ int lds[SCAN_B];
    __shared__ int base_s;
    int tid = threadIdx.x;
    int gid = blockIdx.x * SCAN_B + tid;
    int v = (gid < N_NODES) ? count[gid] : 0;
    lds[tid] = v;
    __syncthreads();
    #pragma unroll
    for (int off = 1; off < SCAN_B; off <<= 1) {
        int t = (tid >= off) ? lds[tid - off] : 0;
        __syncthreads();
        lds[tid] += t;
        __syncthreads();
    }
    if (tid == SCAN_B - 1) base_s = atomicAdd(gcursor, lds[SCAN_B - 1]);
    __syncthreads();
    if (gid < N_NODES) starts[gid] = base_s + lds[tid] - v;   // exclusive
}

// --- Kernel 3: place packed payload {src|rel<<17, exp(att)} into CSR slots.
// Post-increments starts[] (afterwards starts[d] == segment end).
__global__ void place_kernel(const int* __restrict__ ei,
                             const int* __restrict__ ej,
                             const int* __restrict__ rel,
                             const float* __restrict__ s_i,
                             const float* __restrict__ s_j,
                             const float* __restrict__ s_r,
                             int* __restrict__ starts,
                             int2* __restrict__ pack) {
    int e = blockIdx.x * blockDim.x + threadIdx.x;
    if (e >= N_EDGES) return;
    int d   = ei[e];
    int src = ej[e];
    int r   = rel[e];
    float se = __expf(s_i[d] + s_r[r] + s_j[src]);  // |att| small: no max pass
    int pos = atomicAdd(&starts[d], 1);
    pack[pos] = make_int2(src | (r << SRC_BITS), __float_as_int(se));
}

// --- Kernel 4: aggregate. 16 lanes per node (4 nodes/wave), float4 gathers,
// x4 edge unroll -> up to 16 outstanding row-gathers per wave. No cross-lane
// reductions needed: each lane owns 4 x-cols and 2 rel-cols; S replicates.
__global__ void node_aggregate_kernel(const int2* __restrict__ pack,
                                      const int* __restrict__ starts_end,
                                      const int* __restrict__ count,
                                      const float* __restrict__ x,
                                      const float* __restrict__ rel_emb,
                                      float* __restrict__ out) {
    int t    = blockIdx.x * blockDim.x + threadIdx.x;
    int node = t >> 4;          // N_NODES*16 threads exactly (100000%16==0 grid math below)
    int sub  = t & 15;
    if (node >= N_NODES) return;
    int cnt = count[node];
    int end = starts_end[node];
    int beg = end - cnt;
    float S = 0.0f;
    float4 accx = make_float4(0.f, 0.f, 0.f, 0.f);
    float2 accr = make_float2(0.f, 0.f);
    int k = 0;
    for (; k + 4 <= cnt; k += 4) {
        int2 p0 = pack[beg + k + 0];
        int2 p1 = pack[beg + k + 1];
        int2 p2 = pack[beg + k + 2];
        int2 p3 = pack[beg + k + 3];
        int s0 = p0.x & SRC_MASK, r0 = (unsigned)p0.x >> SRC_BITS;
        int s1 = p1.x & SRC_MASK, r1 = (unsigned)p1.x >> SRC_BITS;
        int s2 = p2.x & SRC_MASK, r2 = (unsigned)p2.x >> SRC_BITS;
        int s3 = p3.x & SRC_MASK, r3 = (unsigned)p3.x >> SRC_BITS;
        float4 x0 = *(const float4*)&x[s0 * E_HID + sub * 4];
        float4 x1 = *(const float4*)&x[s1 * E_HID + sub * 4];
        float4 x2 = *(const float4*)&x[s2 * E_HID + sub * 4];
        float4 x3 = *(const float4*)&x[s3 * E_HID + sub * 4];
        float2 e0 = *(const float2*)&rel_emb[r0 * R_HID + sub * 2];
        float2 e1 = *(const float2*)&rel_emb[r1 * R_HID + sub * 2];
        float2 e2 = *(const float2*)&rel_emb[r2 * R_HID + sub * 2];
        float2 e3 = *(const float2*)&rel_emb[r3 * R_HID + sub * 2];
        float se0 = __int_as_float(p0.y), se1 = __int_as_float(p1.y);
        float se2 = __int_as_float(p2.y), se3 = __int_as_float(p3.y);
        S += (se0 + se1) + (se2 + se3);
        accx = axpy4(se0, x0, accx); accx = axpy4(se1, x1, accx);
        accx = axpy4(se2, x2, accx); accx = axpy4(se3, x3, accx);
        accr.x += se0 * e0.x + se1 * e1.x + se2 * e2.x + se3 * e3.x;
        accr.y += se0 * e0.y + se1 * e1.y + se2 * e2.y + se3 * e3.y;
    }
    for (; k < cnt; k++) {
        int2 p = pack[beg + k];
        int s = p.x & SRC_MASK, r = (unsigned)p.x >> SRC_BITS;
        float se = __int_as_float(p.y);
        float4 xv = *(const float4*)&x[s * E_HID + sub * 4];
        float2 ev = *(const float2*)&rel_emb[r * R_HID + sub * 2];
        S += se;
        accx = axpy4(se, xv, accx);
        accr.x += se * ev.x;
        accr.y += se * ev.y;
    }
    float wv = 1.0f / (S + EPSF);
    float alpha = S * wv;
    float4 xv = *(const float4*)&x[node * E_HID + sub * 4];
    float* o = out + (size_t)node * D_OUT;
    *(float4*)&o[sub * 4] = xv;                               // cols 0:64 = x
    float4 ax = make_float4(fmaxf(alpha * xv.x, 0.f), fmaxf(alpha * xv.y, 0.f),
                            fmaxf(alpha * xv.z, 0.f), fmaxf(alpha * xv.w, 0.f));
    *(float4*)&o[64 + sub * 4] = ax;                          // cols 64:128
    *(float2*)&o[128 + sub * 2] =
        make_float2(fmaxf(accr.x * wv, 0.f), fmaxf(accr.y * wv, 0.f)); // 128:160
    *(float4*)&o[160 + sub * 4] =
        make_float4(fmaxf(accx.x * wv, 0.f), fmaxf(accx.y * wv, 0.f),
                    fmaxf(accx.z * wv, 0.f), fmaxf(accx.w * wv, 0.f)); // 160:224
}

extern "C" void kernel_launch(void* const* d_in, const int* in_sizes, int n_in,
                              void* d_out, int out_size, void* d_ws, size_t ws_size,
                              hipStream_t stream) {
    const float* x        = (const float*)d_in[0];               // [N, 64]
    const int*   edge_all = (const int*)  d_in[1];               // [2, E] flat
    const int*   rel      = (const int*)  d_in[2];               // [E]
    const float* rel_emb  = (const float*)d_in[3];               // [500, 32]
    const float* ww       = (const float*)d_in[4];               // [160]
    float*       out      = (float*)d_out;                       // [N, 224]

    const int* ei = edge_all;            // destinations (group index)
    const int* ej = edge_all + N_EDGES;  // sources

    // workspace: pack[E] (int2, 4MB) | s_i[N] | s_j[N] | s_r[512] |
    //            count[N] | gcursor | starts[N]
    int2*  pack    = (int2*)d_ws;
    float* s_i     = (float*)(pack + N_EDGES);
    float* s_j     = s_i + N_NODES;
    float* s_r     = s_j + N_NODES;
    int*   count   = (int*)(s_r + 512);
    int*   gcursor = count + N_NODES;
    int*   starts  = gcursor + 1;

    // zero count + gcursor in one memset
    hipMemsetAsync(count, 0, (size_t)(N_NODES + 1) * sizeof(int), stream);

    fused_pre_kernel<<<PRE_GRID, 256, 0, stream>>>(x, rel_emb, ww, ei,
                                                   s_i, s_j, s_r, count);
    scan_kernel<<<SCAN_NB, SCAN_B, 0, stream>>>(count, starts, gcursor);
    place_kernel<<<(N_EDGES + 255) / 256, 256, 0, stream>>>(ei, ej, rel,
                                                            s_i, s_j, s_r,
                                                            starts, pack);
    node_aggregate_kernel<<<(N_NODES * 16) / 256, 256, 0, stream>>>(
        pack, starts, count, x, rel_emb, out);
}